// Round 4
// baseline (428.727 us; speedup 1.0000x reference)
//
#include <hip/hip_runtime.h>

#define EPSV 1e-5f

typedef __bf16 bf16x8 __attribute__((ext_vector_type(8)));
typedef float f32x4 __attribute__((ext_vector_type(4)));
typedef unsigned int u32x4 __attribute__((ext_vector_type(4)));
typedef unsigned short u16x4 __attribute__((ext_vector_type(4)));

__device__ __forceinline__ unsigned short f2bf(float f) {
  return __builtin_bit_cast(unsigned short, static_cast<__bf16>(f));
}

constexpr int Himg = 112, Wimg = 112, HWp = Himg * Wimg;  // 12544

// ---------------------------------------------------------------------------
// prep_misc: pack weights into per-lane MFMA A-fragment order + BN scale/shift.
//   wPack[i], i = ((tap*2+ks)*4 + c)*512 + l*8 + j  (bf16)
//   co = c*16+(l&15), ci = ks*32+(l>>4)*8+j
// ---------------------------------------------------------------------------
__global__ __launch_bounds__(256) void prep_misc(
    const float* __restrict__ w1, const float* __restrict__ w2,
    const float* __restrict__ g1, const float* __restrict__ b1,
    const float* __restrict__ m1, const float* __restrict__ v1,
    const float* __restrict__ g2, const float* __restrict__ b2,
    const float* __restrict__ m2, const float* __restrict__ v2,
    unsigned short* __restrict__ wt1, unsigned short* __restrict__ wt2,
    float* __restrict__ prm)
{
  int id = blockIdx.x * 256 + threadIdx.x;
  for (int i = id; i < 9 * 2 * 4 * 512; i += gridDim.x * 256) {
    int j   = i & 7;
    int l   = (i >> 3) & 63;
    int c   = (i >> 9) & 3;
    int ks  = (i >> 11) & 1;
    int tap = i >> 12;
    int co  = c * 16 + (l & 15);
    int ci  = ks * 32 + (l >> 4) * 8 + j;
    int kh  = tap / 3, kw = tap - kh * 3;
    int src = ((co * 64 + ci) * 3 + kh) * 3 + kw;
    wt1[i] = f2bf(w1[src]);
    wt2[i] = f2bf(w2[src]);
  }
  if (id < 64) {
    float s1 = g1[id] * rsqrtf(v1[id] + EPSV);
    prm[id]      = s1;
    prm[64 + id] = b1[id] - m1[id] * s1;
    float s2 = g2[id] * rsqrtf(v2[id] + EPSV);
    prm[128 + id] = s2;
    prm[192 + id] = b2[id] - m2[id] * s2;
  }
}

// ---------------------------------------------------------------------------
// prep_x0: x NCHW f32 -> x0 = BN0(x) as NHWC bf16
// ---------------------------------------------------------------------------
__global__ __launch_bounds__(256) void prep_x0(
    const float* __restrict__ x,
    const float* __restrict__ g0, const float* __restrict__ b0,
    const float* __restrict__ m0, const float* __restrict__ v0,
    unsigned short* __restrict__ x0)
{
  __shared__ float sc[64];
  __shared__ float sh[64];
  __shared__ float tile[64][113];
  const int t = threadIdx.x;
  const int bid = blockIdx.x;          // n*112 + h
  const int n = bid / 112, h = bid - n * 112;
  if (t < 64) {
    float s = g0[t] * rsqrtf(v0[t] + EPSV);
    sc[t] = s;
    sh[t] = b0[t] - m0[t] * s;
  }
  __syncthreads();
  const float* xp = x + (size_t)n * 64 * HWp + h * Wimg;
  for (int i = t; i < 64 * Wimg; i += 256) {
    int c = i / Wimg, w = i - c * Wimg;
    tile[c][w] = xp[(size_t)c * HWp + w] * sc[c] + sh[c];
  }
  __syncthreads();
  unsigned short* op = x0 + (size_t)bid * Wimg * 64;
  for (int i = t * 4; i < Wimg * 64; i += 1024) {
    int w = i >> 6, c = i & 63;
    u16x4 u;
    u[0] = f2bf(tile[c + 0][w]);
    u[1] = f2bf(tile[c + 1][w]);
    u[2] = f2bf(tile[c + 2][w]);
    u[3] = f2bf(tile[c + 3][w]);
    *reinterpret_cast<u16x4*>(op + i) = u;
  }
}

// ---------------------------------------------------------------------------
// conv3x3s<STAGE>: implicit-GEMM 3x3 conv, weights in LDS, K split by ci-half.
//   block: 448 thr = 7 waves; tile = 4 rows x 112 w x 64 co (grid 1792, 7/CU)
//   wave wv = w-span [wv*16, wv*16+16), all 4 rows, all 64 co
//   per ks half (ci 32):
//     stage patch [6 rows][57 pairQ][128B]  (43776 B, pair XOR swizzle)
//         + weights [9 tap][4 c][1024B]     (36864 B, linear)
//     -> barrier -> 9 taps x (4 wf + 4 pf ds_read_b128, 16 MFMA) -> barrier
//   LDS total 80640 B -> 2 blocks/CU (14 waves). Zero global loads in K-loop.
//   D[co][pixel]: co = c*16+grp*4+reg, pixel(w) = wv*16+lo
// ---------------------------------------------------------------------------
template <int STAGE>
__global__ __launch_bounds__(448, 4) void conv3x3s(
    const unsigned short* __restrict__ src,   // bf16 NHWC [P][64]
    const unsigned short* __restrict__ wP,    // packed bf16 fragments
    const float* __restrict__ scale, const float* __restrict__ shift,
    const float* __restrict__ aP,
    unsigned short* __restrict__ dstb,        // STAGE 1 out
    float* __restrict__ dstf,                 // STAGE 2 out
    const float* __restrict__ resid)          // STAGE 2 residual
{
  constexpr int WOFF = 43776;                 // patch bytes
  constexpr int RS   = 57 * 128;              // patch row stride = 7296 B
  __shared__ __align__(16) unsigned char lds[WOFF + 36864];  // 80640 B
  const int t = threadIdx.x;
  // XCD-chunked bijective swizzle: 1792 = 8 * 224
  const int b = blockIdx.x;
  const int swz = (b & 7) * 224 + (b >> 3);
  const int n = swz / 28, rg = swz - n * 28;
  const int r0 = rg * 4;
  const size_t ibase = (size_t)n * HWp;

  const int wv = t >> 6, l = t & 63;
  const int lo = l & 15, grp = l >> 4;

  f32x4 acc[4][4];
#pragma unroll
  for (int c = 0; c < 4; ++c)
#pragma unroll
    for (int p = 0; p < 4; ++p) {
      f32x4 z = {0.f, 0.f, 0.f, 0.f};
      acc[c][p] = z;
    }

#pragma unroll
  for (int ks = 0; ks < 2; ++ks) {
    if (ks) __syncthreads();   // compute(ks=0) done before restaging

    // ---- stage patch half: rows r0-1..r0+4, 114 wpad, 32 ci (4 chunks) ----
    for (int i = t; i < 6 * 114 * 4; i += 448) {
      int s = i / 456, rem = i - s * 456;
      int P = rem >> 2, k = rem & 3;
      int hh = r0 - 1 + s, w = P - 1;
      u32x4 val = {0u, 0u, 0u, 0u};
      if ((unsigned)hh < 112u && (unsigned)w < 112u)
        val = *reinterpret_cast<const u32x4*>(
            src + (ibase + hh * Wimg + w) * 64 + ks * 32 + k * 8);
      int Q = P >> 1, c8 = ((P & 1) << 2) | k;
      *reinterpret_cast<u32x4*>(&lds[s * RS + Q * 128 + ((c8 ^ (Q & 7)) << 4)]) = val;
    }
    // ---- stage weight half: [9 tap][4 c][1024B] ----
    for (int i = t; i < 2304; i += 448) {
      int f = i >> 6, off = i & 63;          // f = tap*4+c
      int chunk = ((f >> 2) * 8 + ks * 4 + (f & 3)) * 64 + off;
      u32x4 v = *reinterpret_cast<const u32x4*>(wP + chunk * 8);
      *reinterpret_cast<u32x4*>(&lds[WOFF + i * 16]) = v;
    }
    __syncthreads();

    // ---- K-loop: 9 taps, all indices static after unroll ----
#pragma unroll
    for (int tap = 0; tap < 9; ++tap) {
      const int dh = tap / 3, dw = tap - dh * 3;
      bf16x8 wf[4], pf[4];
#pragma unroll
      for (int c = 0; c < 4; ++c)
        wf[c] = *reinterpret_cast<const bf16x8*>(&lds[WOFF + (tap * 4 + c) * 1024 + l * 16]);
      const int Ps = wv * 16 + lo + dw;
      const int Q = Ps >> 1, c8 = ((Ps & 1) << 2) | grp;
      const int pbyte = Q * 128 + ((c8 ^ (Q & 7)) << 4);
#pragma unroll
      for (int p = 0; p < 4; ++p)
        pf[p] = *reinterpret_cast<const bf16x8*>(&lds[(p + dh) * RS + pbyte]);
#pragma unroll
      for (int c = 0; c < 4; ++c)
#pragma unroll
        for (int p = 0; p < 4; ++p)
          acc[c][p] = __builtin_amdgcn_mfma_f32_16x16x32_bf16(wf[c], pf[p], acc[c][p], 0, 0, 0);
    }
  }

  // ---- epilogue ----  D[co][pixel]: co = c*16+grp*4+j, w = wv*16+lo
#pragma unroll
  for (int c = 0; c < 4; ++c) {
    const int co0 = c * 16 + grp * 4;
    float s_[4], h_[4], a_[4];
#pragma unroll
    for (int j = 0; j < 4; ++j) {
      s_[j] = scale[co0 + j];
      h_[j] = shift[co0 + j];
      a_[j] = aP[co0 + j];
    }
    const int w = wv * 16 + lo;
#pragma unroll
    for (int p = 0; p < 4; ++p) {
      const int hh = r0 + p;
      f32x4 v = acc[c][p];
      if (STAGE == 1) {
        u16x4 u;
#pragma unroll
        for (int j = 0; j < 4; ++j) {
          float vv = v[j] * s_[j] + h_[j];
          vv = vv >= 0.f ? vv : vv * a_[j];
          u[j] = f2bf(vv);
        }
        *reinterpret_cast<u16x4*>(dstb + (ibase + hh * Wimg + w) * 64 + co0) = u;
      } else {
#pragma unroll
        for (int j = 0; j < 4; ++j) {
          size_t idx = ((size_t)(n * 64 + co0 + j) * Himg + hh) * Wimg + w;
          float vv = v[j] * s_[j] + h_[j] + resid[idx];
          vv = vv >= 0.f ? vv : vv * a_[j];
          dstf[idx] = vv;
        }
      }
    }
  }
}

// ---------------------------------------------------------------------------
// scratch map:
//   d_out[0 .. 102,760,448)     : x0 bf16 NHWC (dead before conv2 writes)
//   d_ws [0 .. 102,760,448)     : y1 bf16 NHWC
//   d_ws [+0 .. +73,728)        : wt1 packed bf16
//   d_ws [+73,728 .. +147,456)  : wt2 packed bf16
//   d_ws [+147,456 .. +148,480) : prm f32
// ---------------------------------------------------------------------------
extern "C" void kernel_launch(void* const* d_in, const int* in_sizes, int n_in,
                              void* d_out, int out_size, void* d_ws, size_t ws_size,
                              hipStream_t stream)
{
  const float* x  = (const float*)d_in[0];
  const float* w1 = (const float*)d_in[1];
  const float* w2 = (const float*)d_in[2];
  const float* g0 = (const float*)d_in[3];
  const float* b0 = (const float*)d_in[4];
  const float* m0 = (const float*)d_in[5];
  const float* v0 = (const float*)d_in[6];
  const float* g1 = (const float*)d_in[7];
  const float* b1 = (const float*)d_in[8];
  const float* m1 = (const float*)d_in[9];
  const float* v1 = (const float*)d_in[10];
  const float* g2 = (const float*)d_in[11];
  const float* b2 = (const float*)d_in[12];
  const float* m2 = (const float*)d_in[13];
  const float* v2 = (const float*)d_in[14];
  const float* a1 = (const float*)d_in[15];
  const float* a2 = (const float*)d_in[16];

  unsigned short* x0 = (unsigned short*)d_out;
  unsigned char* wsb = (unsigned char*)d_ws;
  unsigned short* y1  = (unsigned short*)wsb;
  unsigned short* wt1 = (unsigned short*)(wsb + 102760448);
  unsigned short* wt2 = (unsigned short*)(wsb + 102760448 + 73728);
  float* prm          = (float*)(wsb + 102760448 + 2 * 73728);

  prep_misc<<<16, 256, 0, stream>>>(w1, w2, g1, b1, m1, v1, g2, b2, m2, v2, wt1, wt2, prm);
  prep_x0<<<64 * 112, 256, 0, stream>>>(x, g0, b0, m0, v0, x0);
  conv3x3s<1><<<1792, 448, 0, stream>>>(x0, wt1, prm, prm + 64, a1, y1, nullptr, nullptr);
  conv3x3s<2><<<1792, 448, 0, stream>>>(y1, wt2, prm + 128, prm + 192, a2, nullptr, (float*)d_out, x);
}